// Round 1
// baseline (368.414 us; speedup 1.0000x reference)
//
#include <hip/hip_runtime.h>
#include <hip/hip_bf16.h>
#include <math.h>

// ---------------------------------------------------------------------------
// GCN 2-layer. A_hat = D^-1/2 (A+I) D^-1/2 factored: scale GEMM rows by dinv
// (epilogue), gather-sum neighbors, scale by dinv[dst], add self term.
// Round 8: CSR build with ZERO per-edge global atomics (two-level counting
// sort: partA buckets by dst>>8 with LDS hist, partB per-bucket degree hist).
// Round 9: gemm1 rewritten as barrier-free register-resident MFMA
// (wave-per-16-rows, K split in halves with async-stage prefetch). The old
// LDS-staged version was latency-bound: MfmaUtil 3.6%, HBM 12%, 65 us.
// ---------------------------------------------------------------------------

#define FEAT1 512
#define FEAT2 128
#define FEAT3 40

typedef __attribute__((ext_vector_type(8))) short bf16x8;
typedef __attribute__((ext_vector_type(4))) float f32x4;

__device__ __forceinline__ unsigned short f2bf(float f) {
    union { float f; unsigned u; } c; c.f = f;
    unsigned r = c.u + 0x7fff + ((c.u >> 16) & 1);   // round-nearest-even
    return (unsigned short)(r >> 16);
}
__device__ __forceinline__ float bf2f(unsigned v16) {
    union { unsigned u; float f; } c; c.u = v16 << 16;
    return c.f;
}

__device__ __forceinline__ bf16x8 pack_bf8(f32x4 a, f32x4 b) {
    bf16x8 r;
    r[0] = (short)f2bf(a[0]); r[1] = (short)f2bf(a[1]);
    r[2] = (short)f2bf(a[2]); r[3] = (short)f2bf(a[3]);
    r[4] = (short)f2bf(b[0]); r[5] = (short)f2bf(b[1]);
    r[6] = (short)f2bf(b[2]); r[7] = (short)f2bf(b[3]);
    return r;
}

// ---- edge_index may be int32 (JAX default) or int64. -----------------------
__global__ void detect_i64_kernel(const int* __restrict__ ei, int* flagp) {
    __shared__ int any;
    if (threadIdx.x == 0) any = 0;
    __syncthreads();
    int v = ei[2 * threadIdx.x + 1];
    if (v != 0) any = 1;
    __syncthreads();
    if (threadIdx.x == 0) *flagp = (any == 0) ? 1 : 0;   // 1 => int64 layout
}

__device__ __forceinline__ int load_src(const int* ei, long e, long E, int f64) {
    return f64 ? ei[2 * e] : ei[e];
}
__device__ __forceinline__ int load_dst(const int* ei, long e, long E, int f64) {
    return f64 ? ei[2 * E + 2 * e] : ei[E + e];
}

// ---- partA: bucket edges by dst>>8; LDS hist; 1 global claim/bucket/block --
__launch_bounds__(1024)
__global__ void partA_kernel(const int* __restrict__ ei, const int* __restrict__ flagp,
                             int* __restrict__ gbkt, unsigned* __restrict__ part,
                             int bktCap, long E, int NB) {
    __shared__ int hist[256], lbase[256], lcur[256];
    int f64 = *flagp;
    int t = threadIdx.x;
    long chunk = (E + gridDim.x - 1) / gridDim.x;
    long start = (long)blockIdx.x * chunk;
    long end = start + chunk; if (end > E) end = E;
    if (t < 256) { hist[t] = 0; lcur[t] = 0; }
    __syncthreads();

    for (long e0 = start; e0 < end; e0 += 1024) {
        long e = e0 + t;
        if (e < end) {
            int dst = load_dst(ei, e, E, f64);
            atomicAdd(&hist[dst >> 8], 1);
        }
    }
    __syncthreads();
    if (t < NB && hist[t]) lbase[t] = atomicAdd(&gbkt[t], hist[t]);
    __syncthreads();

    for (long e0 = start; e0 < end; e0 += 1024) {
        long e = e0 + t;
        if (e < end) {
            int src = load_src(ei, e, E, f64);
            int dst = load_dst(ei, e, E, f64);
            int bkt = dst >> 8;
            int pos = lbase[bkt] + atomicAdd(&lcur[bkt], 1);
            if (pos < bktCap)
                part[(long)bkt * bktCap + pos] = (unsigned)src | ((unsigned)(dst & 255) << 17);
        }
    }
}

// ---- bscan: exclusive prefix over bucket totals ----------------------------
__global__ void bscan_kernel(const int* __restrict__ gbkt, int* __restrict__ bktBase,
                             int* __restrict__ offsets, int NB, int N, int E) {
    __shared__ int s[256];
    int t = threadIdx.x;
    int v = (t < NB) ? gbkt[t] : 0;
    s[t] = v;
    __syncthreads();
    #pragma unroll
    for (int d = 1; d < 256; d <<= 1) {
        int tv = (t >= d) ? s[t - d] : 0;
        __syncthreads();
        s[t] += tv;
        __syncthreads();
    }
    bktBase[t] = s[t] - v;
    if (t == 0) offsets[N] = E;
}

// ---- partB: per-bucket degree hist + scan -> offsets/dinv; scatter col -----
__launch_bounds__(256)
__global__ void partB_kernel(const unsigned* __restrict__ part, int bktCap,
                             const int* __restrict__ gbkt, const int* __restrict__ bktBase,
                             int* __restrict__ offsets, float* __restrict__ dinv,
                             int* __restrict__ col, int N) {
    __shared__ int h[256], sc[256], cur[256];
    int b = blockIdx.x, t = threadIdx.x;
    int n = gbkt[b]; if (n > bktCap) n = bktCap;
    int base = bktBase[b];
    int lo = b << 8;
    const unsigned* p = part + (long)b * bktCap;
    h[t] = 0;
    __syncthreads();
    for (int i = t; i < n; i += 256) atomicAdd(&h[(p[i] >> 17) & 255], 1);
    __syncthreads();
    int cnt = h[t];
    sc[t] = cnt;
    __syncthreads();
    #pragma unroll
    for (int d = 1; d < 256; d <<= 1) {
        int tv = (t >= d) ? sc[t - d] : 0;
        __syncthreads();
        sc[t] += tv;
        __syncthreads();
    }
    int ex = sc[t] - cnt;
    int node = lo + t;
    if (node < N) {
        offsets[node] = base + ex;
        dinv[node] = 1.0f / sqrtf((float)(cnt + 1));   // +1 self-loop
    }
    cur[t] = ex;
    __syncthreads();
    for (int i = t; i < n; i += 256) {
        unsigned u = p[i];
        int r = atomicAdd(&cur[(u >> 17) & 255], 1);
        col[base + r] = u & 0x1FFFF;
    }
}

// ---- W1 [512,128] f32 -> Bt [128][512] bf16 (n-major, k-contiguous) --------
__global__ void w1bt_kernel(const float* __restrict__ W1, unsigned short* __restrict__ Bt) {
    int n = blockIdx.x;
    for (int k = threadIdx.x; k < FEAT1; k += blockDim.x)
        Bt[(long)n * FEAT1 + k] = f2bf(W1[(long)k * FEAT2 + n]);
}

// ---- W2 [128,40] f32 -> Bt2 [48][128] bf16 (n-major, k-contiguous, 0-pad) --
__global__ void w2bt_kernel(const float* __restrict__ W2, unsigned short* __restrict__ Bt2) {
    int n = blockIdx.x;            // 0..47
    for (int k = threadIdx.x; k < FEAT2; k += blockDim.x)
        Bt2[(long)n * FEAT2 + k] = (n < FEAT3) ? f2bf(W2[(long)k * FEAT3 + n]) : 0;
}

// ---- GEMM1 (MFMA, reg-resident): [M,512]f32 x Bt[128][512]bf16 -> h1s bf16 -
// Wave-per-16-rows, no LDS, no barriers. A fragments loaded directly from
// global (lane l and l+16 cover 64B contiguous of row l&15 -> full lines),
// converted f32->bf16 in-register. K split in two halves; half-2 loads are
// issued BEFORE half-1's MFMA block so HBM latency hides under compute.
// A-row clamp: A row m only affects C row m, so padding rows duplicate M-1
// and their outputs are simply not written (same trick as gemm2).
__launch_bounds__(256)
__global__ void gemm1_reg_kernel(const float* __restrict__ A,
                                 const unsigned short* __restrict__ Bt,
                                 const float* __restrict__ dinv,
                                 unsigned short* __restrict__ C, int M) {
    int wave = blockIdx.x * 4 + (threadIdx.x >> 6);
    int lane = threadIdx.x & 63;
    int quad = lane >> 4, r15 = lane & 15;
    int row0 = wave * 16;
    if (row0 >= M) return;
    int arow = row0 + r15;
    if (arow >= M) arow = M - 1;
    const float* ap = A + (long)arow * FEAT1 + quad * 8;
    const unsigned short* bp = Bt + (long)r15 * FEAT1 + quad * 8;

    // half 0 loads: k = 0..255 (ks = 0..7), 16 independent dwordx4 in flight
    f32x4 raw[16];
    #pragma unroll
    for (int ks = 0; ks < 8; ks++) {
        raw[2 * ks]     = *(const f32x4*)(ap + ks * 32);
        raw[2 * ks + 1] = *(const f32x4*)(ap + ks * 32 + 4);
    }

    f32x4 acc[8];
    #pragma unroll
    for (int nt = 0; nt < 8; nt++) acc[nt] = (f32x4){0.f, 0.f, 0.f, 0.f};

    bf16x8 af[8];
    #pragma unroll
    for (int ks = 0; ks < 8; ks++) af[ks] = pack_bf8(raw[2 * ks], raw[2 * ks + 1]);

    // issue half-1 loads (k = 256..511) before computing half 0
    #pragma unroll
    for (int ks = 0; ks < 8; ks++) {
        raw[2 * ks]     = *(const f32x4*)(ap + 256 + ks * 32);
        raw[2 * ks + 1] = *(const f32x4*)(ap + 256 + ks * 32 + 4);
    }

    #pragma unroll
    for (int ks = 0; ks < 8; ks++) {
        #pragma unroll
        for (int nt = 0; nt < 8; nt++) {
            bf16x8 bfrag = *(const bf16x8*)(bp + (long)nt * 16 * FEAT1 + ks * 32);
            acc[nt] = __builtin_amdgcn_mfma_f32_16x16x32_bf16(af[ks], bfrag, acc[nt], 0, 0, 0);
        }
    }

    #pragma unroll
    for (int ks = 0; ks < 8; ks++) af[ks] = pack_bf8(raw[2 * ks], raw[2 * ks + 1]);

    #pragma unroll
    for (int ks = 0; ks < 8; ks++) {
        #pragma unroll
        for (int nt = 0; nt < 8; nt++) {
            bf16x8 bfrag = *(const bf16x8*)(bp + (long)nt * 16 * FEAT1 + 256 + ks * 32);
            acc[nt] = __builtin_amdgcn_mfma_f32_16x16x32_bf16(af[ks], bfrag, acc[nt], 0, 0, 0);
        }
    }

    // C/D: col=lane&15, row=quad*4+reg
    #pragma unroll
    for (int reg = 0; reg < 4; reg++) {
        int orow = row0 + quad * 4 + reg;
        if (orow >= M) continue;
        float di = dinv[orow];
        #pragma unroll
        for (int nt = 0; nt < 8; nt++)
            C[(long)orow * FEAT2 + nt * 16 + r15] = f2bf(acc[nt][reg] * di);
    }
}

// ---- Aggregation 1: wave-per-node; shfl-broadcast col; writes bf16 a1 -------
__launch_bounds__(256)
__global__ void agg1_kernel(const unsigned short* __restrict__ h1s,
                            const int* __restrict__ col, const int* __restrict__ off,
                            const float* __restrict__ dinv, const float* __restrict__ b1,
                            unsigned short* __restrict__ a1, int N) {
    int node = blockIdx.x * 4 + (threadIdx.x >> 6);
    if (node >= N) return;
    int l = threadIdx.x & 63;            // lane handles feats 2l, 2l+1
    int o0 = off[node], o1 = off[node + 1];
    float ax = 0.f, ay = 0.f;
    for (int base = o0; base < o1; base += 64) {
        int cnt = min(64, o1 - base);
        int myc = (l < cnt) ? col[base + l] : 0;
        int e = 0;
        for (; e + 4 <= cnt; e += 4) {
            int s0 = __shfl(myc, e + 0);
            int s1 = __shfl(myc, e + 1);
            int s2 = __shfl(myc, e + 2);
            int s3 = __shfl(myc, e + 3);
            unsigned p0 = *(const unsigned*)(h1s + (long)s0 * FEAT2 + 2 * l);
            unsigned p1 = *(const unsigned*)(h1s + (long)s1 * FEAT2 + 2 * l);
            unsigned p2 = *(const unsigned*)(h1s + (long)s2 * FEAT2 + 2 * l);
            unsigned p3 = *(const unsigned*)(h1s + (long)s3 * FEAT2 + 2 * l);
            ax += bf2f(p0 & 0xffffu) + bf2f(p1 & 0xffffu) +
                  bf2f(p2 & 0xffffu) + bf2f(p3 & 0xffffu);
            ay += bf2f(p0 >> 16) + bf2f(p1 >> 16) + bf2f(p2 >> 16) + bf2f(p3 >> 16);
        }
        for (; e < cnt; ++e) {
            int s = __shfl(myc, e);
            unsigned p = *(const unsigned*)(h1s + (long)s * FEAT2 + 2 * l);
            ax += bf2f(p & 0xffffu);
            ay += bf2f(p >> 16);
        }
    }
    unsigned pv = *(const unsigned*)(h1s + (long)node * FEAT2 + 2 * l);  // self
    ax += bf2f(pv & 0xffffu);
    ay += bf2f(pv >> 16);
    float di = dinv[node];
    float2 b = *(const float2*)(b1 + 2 * l);
    float vx = ax * di + b.x;
    float vy = ay * di + b.y;
    vx = vx > 0.f ? vx : 0.f;
    vy = vy > 0.f ? vy : 0.f;
    *(unsigned*)(a1 + (long)node * FEAT2 + 2 * l) =
        (unsigned)f2bf(vx) | ((unsigned)f2bf(vy) << 16);
}

// ---- GEMM2 (MFMA): a1[M,128]bf16 x Bt2[48][128]bf16 -> h2s bf16, *dinv -----
__launch_bounds__(256)
__global__ void gemm2_mfma_kernel(const unsigned short* __restrict__ A,
                                  const unsigned short* __restrict__ Bt2,
                                  const float* __restrict__ dinv,
                                  unsigned short* __restrict__ C, int M) {
    int wave = blockIdx.x * (blockDim.x >> 6) + (threadIdx.x >> 6);
    int lane = threadIdx.x & 63;
    int quad = lane >> 4, r15 = lane & 15;
    int row0 = wave * 16;
    if (row0 >= M) return;
    int arow = row0 + r15;
    if (arow >= M) arow = M - 1;         // clamp: A row m only affects C row m

    bf16x8 af[4];
    const unsigned short* ap = A + (long)arow * FEAT2 + quad * 8;
    #pragma unroll
    for (int ks = 0; ks < 4; ks++) af[ks] = *(const bf16x8*)(ap + ks * 32);

    f32x4 acc[3];
    #pragma unroll
    for (int nt = 0; nt < 3; nt++) acc[nt] = (f32x4){0.f, 0.f, 0.f, 0.f};
    #pragma unroll
    for (int ks = 0; ks < 4; ks++) {
        #pragma unroll
        for (int nt = 0; nt < 3; nt++) {
            bf16x8 bf = *(const bf16x8*)(Bt2 + (long)(nt * 16 + r15) * FEAT2 + ks * 32 + quad * 8);
            acc[nt] = __builtin_amdgcn_mfma_f32_16x16x32_bf16(af[ks], bf, acc[nt], 0, 0, 0);
        }
    }

    // C/D: col=lane&15, row=quad*4+reg
    #pragma unroll
    for (int reg = 0; reg < 4; reg++) {
        int orow = row0 + quad * 4 + reg;
        if (orow >= M) continue;
        float di = dinv[orow];
        #pragma unroll
        for (int nt = 0; nt < 3; nt++) {
            int ocol = nt * 16 + r15;
            if (ocol < FEAT3)
                C[(long)orow * FEAT3 + ocol] = f2bf(acc[nt][reg] * di);
        }
    }
}

// ---- Aggregation 2 + log_softmax: wave-per-node, shfl col, 4-way unroll -----
__launch_bounds__(256)
__global__ void agg2_lsm_kernel(const unsigned short* __restrict__ h2s,
                                const int* __restrict__ col, const int* __restrict__ off,
                                const float* __restrict__ dinv, const float* __restrict__ b2,
                                float* __restrict__ out, int N) {
    int node = blockIdx.x * 4 + (threadIdx.x >> 6);
    if (node >= N) return;
    int l = threadIdx.x & 63;
    bool act = l < FEAT3 / 2;
    int o0 = off[node], o1 = off[node + 1];
    float ax = 0.f, ay = 0.f;
    for (int base = o0; base < o1; base += 64) {
        int cnt = min(64, o1 - base);
        int myc = (l < cnt) ? col[base + l] : 0;
        int e = 0;
        for (; e + 4 <= cnt; e += 4) {
            int s0 = __shfl(myc, e + 0);
            int s1 = __shfl(myc, e + 1);
            int s2 = __shfl(myc, e + 2);
            int s3 = __shfl(myc, e + 3);
            if (act) {
                unsigned p0 = *(const unsigned*)(h2s + (long)s0 * FEAT3 + 2 * l);
                unsigned p1 = *(const unsigned*)(h2s + (long)s1 * FEAT3 + 2 * l);
                unsigned p2 = *(const unsigned*)(h2s + (long)s2 * FEAT3 + 2 * l);
                unsigned p3 = *(const unsigned*)(h2s + (long)s3 * FEAT3 + 2 * l);
                ax += bf2f(p0 & 0xffffu) + bf2f(p1 & 0xffffu) +
                      bf2f(p2 & 0xffffu) + bf2f(p3 & 0xffffu);
                ay += bf2f(p0 >> 16) + bf2f(p1 >> 16) + bf2f(p2 >> 16) + bf2f(p3 >> 16);
            }
        }
        for (; e < cnt; ++e) {
            int s = __shfl(myc, e);
            if (act) {
                unsigned p = *(const unsigned*)(h2s + (long)s * FEAT3 + 2 * l);
                ax += bf2f(p & 0xffffu);
                ay += bf2f(p >> 16);
            }
        }
    }
    float vx = -INFINITY, vy = -INFINITY;
    if (act) {
        unsigned pv = *(const unsigned*)(h2s + (long)node * FEAT3 + 2 * l);  // self
        float di = dinv[node];
        float2 b = *(const float2*)(b2 + 2 * l);
        vx = (ax + bf2f(pv & 0xffffu)) * di + b.x;
        vy = (ay + bf2f(pv >> 16)) * di + b.y;
    }
    float m = fmaxf(vx, vy);
    #pragma unroll
    for (int o = 32; o >= 1; o >>= 1) m = fmaxf(m, __shfl_xor(m, o));
    float e = act ? (expf(vx - m) + expf(vy - m)) : 0.f;
    #pragma unroll
    for (int o = 32; o >= 1; o >>= 1) e += __shfl_xor(e, o);
    float ls = logf(e);
    if (act) {
        *(float2*)(out + (long)node * FEAT3 + 2 * l) = make_float2(vx - m - ls, vy - m - ls);
    }
}

// ---------------------------------------------------------------------------
extern "C" void kernel_launch(void* const* d_in, const int* in_sizes, int n_in,
                              void* d_out, int out_size, void* d_ws, size_t ws_size,
                              hipStream_t stream) {
    const float* x  = (const float*)d_in[0];
    const int*   ei = (const int*)d_in[1];
    const float* W1 = (const float*)d_in[2];
    const float* b1 = (const float*)d_in[3];
    const float* W2 = (const float*)d_in[4];
    const float* b2 = (const float*)d_in[5];
    float* out = (float*)d_out;

    const int  N = in_sizes[0] / FEAT1;       // 50000
    const long E = in_sizes[1] / 2;           // 1600000

    char* ws = (char*)d_ws;
    size_t off = 0;
    auto alloc = [&](size_t bytes) -> void* {
        off = (off + 255) & ~(size_t)255;
        void* p = ws + off;
        off += bytes;
        return p;
    };
    const int NB = (N + 255) >> 8;            // 196 buckets of 256 nodes
    const int bktCap = (int)(E / NB) + 1024;  // mean + >>10 sigma slack
    int*   offsets = (int*)alloc((size_t)(N + 1) * 4);
    float* dinv    = (float*)alloc((size_t)N * 4);
    int*   col     = (int*)alloc((size_t)E * 4);
    unsigned short* h1s = (unsigned short*)alloc((size_t)N * FEAT2 * 2);
    unsigned short* a1  = (unsigned short*)alloc((size_t)N * FEAT2 * 2);
    unsigned short* h2s = (unsigned short*)alloc((size_t)N * FEAT3 * 2);
    unsigned short* Bt  = (unsigned short*)alloc((size_t)FEAT2 * FEAT1 * 2);
    unsigned short* Bt2 = (unsigned short*)alloc((size_t)48 * FEAT2 * 2);
    unsigned* part = (unsigned*)alloc((size_t)NB * bktCap * 4);
    int*   gbkt    = (int*)alloc(256 * 4);
    int*   bktBase = (int*)alloc(256 * 4);
    int*   flagp   = (int*)alloc(4);

    detect_i64_kernel<<<1, 256, 0, stream>>>(ei, flagp);
    hipMemsetAsync(gbkt, 0, 256 * 4, stream);
    partA_kernel<<<256, 1024, 0, stream>>>(ei, flagp, gbkt, part, bktCap, E, NB);
    bscan_kernel<<<1, 256, 0, stream>>>(gbkt, bktBase, offsets, NB, N, (int)E);
    partB_kernel<<<NB, 256, 0, stream>>>(part, bktCap, gbkt, bktBase, offsets, dinv, col, N);

    w1bt_kernel<<<FEAT2, 256, 0, stream>>>(W1, Bt);
    w2bt_kernel<<<48, 128, 0, stream>>>(W2, Bt2);
    {
        int waves = (N + 15) / 16;
        gemm1_reg_kernel<<<(waves + 3) / 4, 256, 0, stream>>>(x, Bt, dinv, h1s, N);
    }
    agg1_kernel<<<(N + 3) / 4, 256, 0, stream>>>(h1s, col, offsets, dinv, b1, a1, N);
    gemm2_mfma_kernel<<<(N / 16 + 3) / 4, 256, 0, stream>>>(a1, Bt2, dinv, h2s, N);
    agg2_lsm_kernel<<<(N + 3) / 4, 256, 0, stream>>>(h2s, col, offsets, dinv, b2, out, N);
}

// Round 2
// 331.423 us; speedup vs baseline: 1.1116x; 1.1116x over previous
//
#include <hip/hip_runtime.h>
#include <hip/hip_bf16.h>
#include <math.h>

// ---------------------------------------------------------------------------
// GCN 2-layer. A_hat = D^-1/2 (A+I) D^-1/2 factored: scale GEMM rows by dinv
// (epilogue), gather-sum neighbors, scale by dinv[dst], add self term.
// Round 8: CSR build with ZERO per-edge global atomics (two-level counting
// sort: partA buckets by dst>>8 with LDS hist, partB per-bucket degree hist).
// Round 10: gemm1 = whole-Bt-in-LDS (128KB, one barrier), wave-per-16-rows,
// direct-to-reg A loads with depth-3 prefetch ring (4x2 f32x4 = 32 VGPR so
// the compiler KEEPS it resident -- round 9's 16-buffer ring got sunk at
// VGPR=60 and serialized; plus B had zero reuse from L2: 400MB @ ~200cy).
// B image is PRE-SWIZZLED in global (chunk16 ^= row&7) so the LDS copy is
// linear and ds_read_b128 XORs the same way -> 2-way conflict (free).
// ---------------------------------------------------------------------------

#define FEAT1 512
#define FEAT2 128
#define FEAT3 40

typedef __attribute__((ext_vector_type(8))) short bf16x8;
typedef __attribute__((ext_vector_type(4))) float f32x4;

__device__ __forceinline__ unsigned short f2bf(float f) {
    union { float f; unsigned u; } c; c.f = f;
    unsigned r = c.u + 0x7fff + ((c.u >> 16) & 1);   // round-nearest-even
    return (unsigned short)(r >> 16);
}
__device__ __forceinline__ float bf2f(unsigned v16) {
    union { unsigned u; float f; } c; c.u = v16 << 16;
    return c.f;
}

// f32x4 pair -> 8 bf16 via v_cvt_pk_bf16_f32 (compiler emits pk from casts)
__device__ __forceinline__ bf16x8 pack_bf8(f32x4 a, f32x4 b) {
    union { __hip_bfloat162 h[4]; bf16x8 v; } u;
    u.h[0] = __float22bfloat162_rn(make_float2(a[0], a[1]));
    u.h[1] = __float22bfloat162_rn(make_float2(a[2], a[3]));
    u.h[2] = __float22bfloat162_rn(make_float2(b[0], b[1]));
    u.h[3] = __float22bfloat162_rn(make_float2(b[2], b[3]));
    return u.v;
}

// ---- edge_index may be int32 (JAX default) or int64. -----------------------
__global__ void detect_i64_kernel(const int* __restrict__ ei, int* flagp) {
    __shared__ int any;
    if (threadIdx.x == 0) any = 0;
    __syncthreads();
    int v = ei[2 * threadIdx.x + 1];
    if (v != 0) any = 1;
    __syncthreads();
    if (threadIdx.x == 0) *flagp = (any == 0) ? 1 : 0;   // 1 => int64 layout
}

__device__ __forceinline__ int load_src(const int* ei, long e, long E, int f64) {
    return f64 ? ei[2 * e] : ei[e];
}
__device__ __forceinline__ int load_dst(const int* ei, long e, long E, int f64) {
    return f64 ? ei[2 * E + 2 * e] : ei[E + e];
}

// ---- partA: bucket edges by dst>>8; LDS hist; 1 global claim/bucket/block --
__launch_bounds__(1024)
__global__ void partA_kernel(const int* __restrict__ ei, const int* __restrict__ flagp,
                             int* __restrict__ gbkt, unsigned* __restrict__ part,
                             int bktCap, long E, int NB) {
    __shared__ int hist[256], lbase[256], lcur[256];
    int f64 = *flagp;
    int t = threadIdx.x;
    long chunk = (E + gridDim.x - 1) / gridDim.x;
    long start = (long)blockIdx.x * chunk;
    long end = start + chunk; if (end > E) end = E;
    if (t < 256) { hist[t] = 0; lcur[t] = 0; }
    __syncthreads();

    for (long e0 = start; e0 < end; e0 += 1024) {
        long e = e0 + t;
        if (e < end) {
            int dst = load_dst(ei, e, E, f64);
            atomicAdd(&hist[dst >> 8], 1);
        }
    }
    __syncthreads();
    if (t < NB && hist[t]) lbase[t] = atomicAdd(&gbkt[t], hist[t]);
    __syncthreads();

    for (long e0 = start; e0 < end; e0 += 1024) {
        long e = e0 + t;
        if (e < end) {
            int src = load_src(ei, e, E, f64);
            int dst = load_dst(ei, e, E, f64);
            int bkt = dst >> 8;
            int pos = lbase[bkt] + atomicAdd(&lcur[bkt], 1);
            if (pos < bktCap)
                part[(long)bkt * bktCap + pos] = (unsigned)src | ((unsigned)(dst & 255) << 17);
        }
    }
}

// ---- bscan: exclusive prefix over bucket totals ----------------------------
__global__ void bscan_kernel(const int* __restrict__ gbkt, int* __restrict__ bktBase,
                             int* __restrict__ offsets, int NB, int N, int E) {
    __shared__ int s[256];
    int t = threadIdx.x;
    int v = (t < NB) ? gbkt[t] : 0;
    s[t] = v;
    __syncthreads();
    #pragma unroll
    for (int d = 1; d < 256; d <<= 1) {
        int tv = (t >= d) ? s[t - d] : 0;
        __syncthreads();
        s[t] += tv;
        __syncthreads();
    }
    bktBase[t] = s[t] - v;
    if (t == 0) offsets[N] = E;
}

// ---- partB: per-bucket degree hist + scan -> offsets/dinv; scatter col -----
__launch_bounds__(256)
__global__ void partB_kernel(const unsigned* __restrict__ part, int bktCap,
                             const int* __restrict__ gbkt, const int* __restrict__ bktBase,
                             int* __restrict__ offsets, float* __restrict__ dinv,
                             int* __restrict__ col, int N) {
    __shared__ int h[256], sc[256], cur[256];
    int b = blockIdx.x, t = threadIdx.x;
    int n = gbkt[b]; if (n > bktCap) n = bktCap;
    int base = bktBase[b];
    int lo = b << 8;
    const unsigned* p = part + (long)b * bktCap;
    h[t] = 0;
    __syncthreads();
    for (int i = t; i < n; i += 256) atomicAdd(&h[(p[i] >> 17) & 255], 1);
    __syncthreads();
    int cnt = h[t];
    sc[t] = cnt;
    __syncthreads();
    #pragma unroll
    for (int d = 1; d < 256; d <<= 1) {
        int tv = (t >= d) ? sc[t - d] : 0;
        __syncthreads();
        sc[t] += tv;
        __syncthreads();
    }
    int ex = sc[t] - cnt;
    int node = lo + t;
    if (node < N) {
        offsets[node] = base + ex;
        dinv[node] = 1.0f / sqrtf((float)(cnt + 1));   // +1 self-loop
    }
    cur[t] = ex;
    __syncthreads();
    for (int i = t; i < n; i += 256) {
        unsigned u = p[i];
        int r = atomicAdd(&cur[(u >> 17) & 255], 1);
        col[base + r] = u & 0x1FFFF;
    }
}

// ---- W1 [512,128] f32 -> Bt [128][512] bf16, PRE-SWIZZLED image ------------
// Row r holds column n=r of W1, k-contiguous, but each 16B chunk c (= k>>3)
// is stored at chunk position c ^ (r&7). gemm1 copies this image linearly
// into LDS and reads with the same XOR -> bank-conflict-free ds_read_b128.
__global__ void w1bt_kernel(const float* __restrict__ W1, unsigned short* __restrict__ Bt) {
    int r = blockIdx.x;                 // 0..127 (output feature n)
    int x7 = r & 7;
    for (int k = threadIdx.x; k < FEAT1; k += blockDim.x) {
        int c = k >> 3, j = k & 7;
        int eo = (((c ^ x7) << 3) | j);
        Bt[(long)r * FEAT1 + eo] = f2bf(W1[(long)k * FEAT2 + r]);
    }
}

// ---- W2 [128,40] f32 -> Bt2 [48][128] bf16 (n-major, k-contiguous, 0-pad) --
__global__ void w2bt_kernel(const float* __restrict__ W2, unsigned short* __restrict__ Bt2) {
    int n = blockIdx.x;            // 0..47
    for (int k = threadIdx.x; k < FEAT2; k += blockDim.x)
        Bt2[(long)n * FEAT2 + k] = (n < FEAT3) ? f2bf(W2[(long)k * FEAT3 + n]) : 0;
}

// ---- GEMM1 (MFMA): [M,512]f32 x Bt[128][512]bf16(swz) -> h1s bf16, *dinv ---
// Whole Bt staged in LDS (128 KB) once; ONE barrier; then barrier-free
// wave-per-16-rows K-unrolled MFMA with depth-3 A-prefetch ring.
#define G1_NW 8   // waves per block (512 threads)
__launch_bounds__(512, 2)
__global__ void gemm1_mfma_kernel(const float* __restrict__ A,
                                  const unsigned short* __restrict__ Bsw,
                                  const float* __restrict__ dinv,
                                  unsigned short* __restrict__ C, int M) {
    __shared__ unsigned short Bl[FEAT2 * FEAT1];   // 128 KB swizzled B image
    int t = threadIdx.x;

    // stage: 512 threads x 16B x 16 rounds = 128 KB, linear copy
    {
        uint4 tmp[16];
        #pragma unroll
        for (int r = 0; r < 16; r++)
            tmp[r] = *(const uint4*)((const char*)Bsw + (size_t)t * 16 + (size_t)r * 8192);
        #pragma unroll
        for (int r = 0; r < 16; r++)
            *(uint4*)((char*)Bl + (size_t)t * 16 + (size_t)r * 8192) = tmp[r];
    }
    __syncthreads();

    int wave = blockIdx.x * G1_NW + (t >> 6);
    int lane = t & 63;
    int quad = lane >> 4, r15 = lane & 15;
    int row0 = wave * 16;
    if (row0 < M) {
        int arow = row0 + r15;
        if (arow >= M) arow = M - 1;     // clamp: A row m only affects C row m
        const float* ap = A + (long)arow * FEAT1 + quad * 8;
        int x7 = r15 & 7;

        f32x4 ra[4][2];                  // depth-3 prefetch ring (32 VGPR)
        #pragma unroll
        for (int p = 0; p < 3; p++) {
            ra[p][0] = *(const f32x4*)(ap + p * 32);
            ra[p][1] = *(const f32x4*)(ap + p * 32 + 4);
        }

        f32x4 acc[8];
        #pragma unroll
        for (int nt = 0; nt < 8; nt++) acc[nt] = (f32x4){0.f, 0.f, 0.f, 0.f};

        #pragma unroll
        for (int ks = 0; ks < 16; ks++) {
            if (ks < 13) {               // static under full unroll
                ra[(ks + 3) & 3][0] = *(const f32x4*)(ap + (ks + 3) * 32);
                ra[(ks + 3) & 3][1] = *(const f32x4*)(ap + (ks + 3) * 32 + 4);
            }
            bf16x8 af = pack_bf8(ra[ks & 3][0], ra[ks & 3][1]);
            #pragma unroll
            for (int nt = 0; nt < 8; nt++) {
                // swizzled chunk: (ks*4 + quad) ^ (r15&7), 16B units
                int eo = (nt * 16 + r15) * FEAT1 + (((ks * 4 + quad) ^ x7) << 3);
                bf16x8 bfrag = *(const bf16x8*)(Bl + eo);
                acc[nt] = __builtin_amdgcn_mfma_f32_16x16x32_bf16(af, bfrag, acc[nt], 0, 0, 0);
            }
        }

        // C/D: col=lane&15, row=quad*4+reg
        #pragma unroll
        for (int reg = 0; reg < 4; reg++) {
            int orow = row0 + quad * 4 + reg;
            if (orow < M) {
                float di = dinv[orow];
                #pragma unroll
                for (int nt = 0; nt < 8; nt++)
                    C[(long)orow * FEAT2 + nt * 16 + r15] = f2bf(acc[nt][reg] * di);
            }
        }
    }
}

// ---- Aggregation 1: wave-per-node; shfl-broadcast col; writes bf16 a1 -------
__launch_bounds__(256)
__global__ void agg1_kernel(const unsigned short* __restrict__ h1s,
                            const int* __restrict__ col, const int* __restrict__ off,
                            const float* __restrict__ dinv, const float* __restrict__ b1,
                            unsigned short* __restrict__ a1, int N) {
    int node = blockIdx.x * 4 + (threadIdx.x >> 6);
    if (node >= N) return;
    int l = threadIdx.x & 63;            // lane handles feats 2l, 2l+1
    int o0 = off[node], o1 = off[node + 1];
    float ax = 0.f, ay = 0.f;
    for (int base = o0; base < o1; base += 64) {
        int cnt = min(64, o1 - base);
        int myc = (l < cnt) ? col[base + l] : 0;
        int e = 0;
        for (; e + 4 <= cnt; e += 4) {
            int s0 = __shfl(myc, e + 0);
            int s1 = __shfl(myc, e + 1);
            int s2 = __shfl(myc, e + 2);
            int s3 = __shfl(myc, e + 3);
            unsigned p0 = *(const unsigned*)(h1s + (long)s0 * FEAT2 + 2 * l);
            unsigned p1 = *(const unsigned*)(h1s + (long)s1 * FEAT2 + 2 * l);
            unsigned p2 = *(const unsigned*)(h1s + (long)s2 * FEAT2 + 2 * l);
            unsigned p3 = *(const unsigned*)(h1s + (long)s3 * FEAT2 + 2 * l);
            ax += bf2f(p0 & 0xffffu) + bf2f(p1 & 0xffffu) +
                  bf2f(p2 & 0xffffu) + bf2f(p3 & 0xffffu);
            ay += bf2f(p0 >> 16) + bf2f(p1 >> 16) + bf2f(p2 >> 16) + bf2f(p3 >> 16);
        }
        for (; e < cnt; ++e) {
            int s = __shfl(myc, e);
            unsigned p = *(const unsigned*)(h1s + (long)s * FEAT2 + 2 * l);
            ax += bf2f(p & 0xffffu);
            ay += bf2f(p >> 16);
        }
    }
    unsigned pv = *(const unsigned*)(h1s + (long)node * FEAT2 + 2 * l);  // self
    ax += bf2f(pv & 0xffffu);
    ay += bf2f(pv >> 16);
    float di = dinv[node];
    float2 b = *(const float2*)(b1 + 2 * l);
    float vx = ax * di + b.x;
    float vy = ay * di + b.y;
    vx = vx > 0.f ? vx : 0.f;
    vy = vy > 0.f ? vy : 0.f;
    *(unsigned*)(a1 + (long)node * FEAT2 + 2 * l) =
        (unsigned)f2bf(vx) | ((unsigned)f2bf(vy) << 16);
}

// ---- GEMM2 (MFMA): a1[M,128]bf16 x Bt2[48][128]bf16 -> h2s bf16, *dinv -----
__launch_bounds__(256)
__global__ void gemm2_mfma_kernel(const unsigned short* __restrict__ A,
                                  const unsigned short* __restrict__ Bt2,
                                  const float* __restrict__ dinv,
                                  unsigned short* __restrict__ C, int M) {
    int wave = blockIdx.x * (blockDim.x >> 6) + (threadIdx.x >> 6);
    int lane = threadIdx.x & 63;
    int quad = lane >> 4, r15 = lane & 15;
    int row0 = wave * 16;
    if (row0 >= M) return;
    int arow = row0 + r15;
    if (arow >= M) arow = M - 1;         // clamp: A row m only affects C row m

    bf16x8 af[4];
    const unsigned short* ap = A + (long)arow * FEAT2 + quad * 8;
    #pragma unroll
    for (int ks = 0; ks < 4; ks++) af[ks] = *(const bf16x8*)(ap + ks * 32);

    f32x4 acc[3];
    #pragma unroll
    for (int nt = 0; nt < 3; nt++) acc[nt] = (f32x4){0.f, 0.f, 0.f, 0.f};
    #pragma unroll
    for (int ks = 0; ks < 4; ks++) {
        #pragma unroll
        for (int nt = 0; nt < 3; nt++) {
            bf16x8 bf = *(const bf16x8*)(Bt2 + (long)(nt * 16 + r15) * FEAT2 + ks * 32 + quad * 8);
            acc[nt] = __builtin_amdgcn_mfma_f32_16x16x32_bf16(af[ks], bf, acc[nt], 0, 0, 0);
        }
    }

    // C/D: col=lane&15, row=quad*4+reg
    #pragma unroll
    for (int reg = 0; reg < 4; reg++) {
        int orow = row0 + quad * 4 + reg;
        if (orow >= M) continue;
        float di = dinv[orow];
        #pragma unroll
        for (int nt = 0; nt < 3; nt++) {
            int ocol = nt * 16 + r15;
            if (ocol < FEAT3)
                C[(long)orow * FEAT3 + ocol] = f2bf(acc[nt][reg] * di);
        }
    }
}

// ---- Aggregation 2 + log_softmax: wave-per-node, shfl col, 4-way unroll -----
__launch_bounds__(256)
__global__ void agg2_lsm_kernel(const unsigned short* __restrict__ h2s,
                                const int* __restrict__ col, const int* __restrict__ off,
                                const float* __restrict__ dinv, const float* __restrict__ b2,
                                float* __restrict__ out, int N) {
    int node = blockIdx.x * 4 + (threadIdx.x >> 6);
    if (node >= N) return;
    int l = threadIdx.x & 63;
    bool act = l < FEAT3 / 2;
    int o0 = off[node], o1 = off[node + 1];
    float ax = 0.f, ay = 0.f;
    for (int base = o0; base < o1; base += 64) {
        int cnt = min(64, o1 - base);
        int myc = (l < cnt) ? col[base + l] : 0;
        int e = 0;
        for (; e + 4 <= cnt; e += 4) {
            int s0 = __shfl(myc, e + 0);
            int s1 = __shfl(myc, e + 1);
            int s2 = __shfl(myc, e + 2);
            int s3 = __shfl(myc, e + 3);
            if (act) {
                unsigned p0 = *(const unsigned*)(h2s + (long)s0 * FEAT3 + 2 * l);
                unsigned p1 = *(const unsigned*)(h2s + (long)s1 * FEAT3 + 2 * l);
                unsigned p2 = *(const unsigned*)(h2s + (long)s2 * FEAT3 + 2 * l);
                unsigned p3 = *(const unsigned*)(h2s + (long)s3 * FEAT3 + 2 * l);
                ax += bf2f(p0 & 0xffffu) + bf2f(p1 & 0xffffu) +
                      bf2f(p2 & 0xffffu) + bf2f(p3 & 0xffffu);
                ay += bf2f(p0 >> 16) + bf2f(p1 >> 16) + bf2f(p2 >> 16) + bf2f(p3 >> 16);
            }
        }
        for (; e < cnt; ++e) {
            int s = __shfl(myc, e);
            if (act) {
                unsigned p = *(const unsigned*)(h2s + (long)s * FEAT3 + 2 * l);
                ax += bf2f(p & 0xffffu);
                ay += bf2f(p >> 16);
            }
        }
    }
    float vx = -INFINITY, vy = -INFINITY;
    if (act) {
        unsigned pv = *(const unsigned*)(h2s + (long)node * FEAT3 + 2 * l);  // self
        float di = dinv[node];
        float2 b = *(const float2*)(b2 + 2 * l);
        vx = (ax + bf2f(pv & 0xffffu)) * di + b.x;
        vy = (ay + bf2f(pv >> 16)) * di + b.y;
    }
    float m = fmaxf(vx, vy);
    #pragma unroll
    for (int o = 32; o >= 1; o >>= 1) m = fmaxf(m, __shfl_xor(m, o));
    float e = act ? (expf(vx - m) + expf(vy - m)) : 0.f;
    #pragma unroll
    for (int o = 32; o >= 1; o >>= 1) e += __shfl_xor(e, o);
    float ls = logf(e);
    if (act) {
        *(float2*)(out + (long)node * FEAT3 + 2 * l) = make_float2(vx - m - ls, vy - m - ls);
    }
}

// ---------------------------------------------------------------------------
extern "C" void kernel_launch(void* const* d_in, const int* in_sizes, int n_in,
                              void* d_out, int out_size, void* d_ws, size_t ws_size,
                              hipStream_t stream) {
    const float* x  = (const float*)d_in[0];
    const int*   ei = (const int*)d_in[1];
    const float* W1 = (const float*)d_in[2];
    const float* b1 = (const float*)d_in[3];
    const float* W2 = (const float*)d_in[4];
    const float* b2 = (const float*)d_in[5];
    float* out = (float*)d_out;

    const int  N = in_sizes[0] / FEAT1;       // 50000
    const long E = in_sizes[1] / 2;           // 1600000

    char* ws = (char*)d_ws;
    size_t off = 0;
    auto alloc = [&](size_t bytes) -> void* {
        off = (off + 255) & ~(size_t)255;
        void* p = ws + off;
        off += bytes;
        return p;
    };
    const int NB = (N + 255) >> 8;            // 196 buckets of 256 nodes
    const int bktCap = (int)(E / NB) + 1024;  // mean + >>10 sigma slack
    int*   offsets = (int*)alloc((size_t)(N + 1) * 4);
    float* dinv    = (float*)alloc((size_t)N * 4);
    int*   col     = (int*)alloc((size_t)E * 4);
    unsigned short* h1s = (unsigned short*)alloc((size_t)N * FEAT2 * 2);
    unsigned short* a1  = (unsigned short*)alloc((size_t)N * FEAT2 * 2);
    unsigned short* h2s = (unsigned short*)alloc((size_t)N * FEAT3 * 2);
    unsigned short* Bt  = (unsigned short*)alloc((size_t)FEAT2 * FEAT1 * 2);
    unsigned short* Bt2 = (unsigned short*)alloc((size_t)48 * FEAT2 * 2);
    unsigned* part = (unsigned*)alloc((size_t)NB * bktCap * 4);
    int*   gbkt    = (int*)alloc(256 * 4);
    int*   bktBase = (int*)alloc(256 * 4);
    int*   flagp   = (int*)alloc(4);

    detect_i64_kernel<<<1, 256, 0, stream>>>(ei, flagp);
    hipMemsetAsync(gbkt, 0, 256 * 4, stream);
    partA_kernel<<<256, 1024, 0, stream>>>(ei, flagp, gbkt, part, bktCap, E, NB);
    bscan_kernel<<<1, 256, 0, stream>>>(gbkt, bktBase, offsets, NB, N, (int)E);
    partB_kernel<<<NB, 256, 0, stream>>>(part, bktCap, gbkt, bktBase, offsets, dinv, col, N);

    w1bt_kernel<<<FEAT2, 256, 0, stream>>>(W1, Bt);
    w2bt_kernel<<<48, 128, 0, stream>>>(W2, Bt2);
    {
        int waves  = (N + 15) / 16;                    // 3125 row-tiles
        int blocks = (waves + G1_NW - 1) / G1_NW;      // 391
        gemm1_mfma_kernel<<<blocks, 512, 0, stream>>>(x, Bt, dinv, h1s, N);
    }
    agg1_kernel<<<(N + 3) / 4, 256, 0, stream>>>(h1s, col, offsets, dinv, b1, a1, N);
    gemm2_mfma_kernel<<<(N / 16 + 3) / 4, 256, 0, stream>>>(a1, Bt2, dinv, h2s, N);
    agg2_lsm_kernel<<<(N + 3) / 4, 256, 0, stream>>>(h2s, col, offsets, dinv, b2, out, N);
}